// Round 5
// baseline (307.151 us; speedup 1.0000x reference)
//
#include <hip/hip_runtime.h>
#include <hip/hip_bf16.h>
#include <stdint.h>

#define D_MODEL 1024
#define NHEAD 8
#define HDIM 128
#define BATCH 2
#define SEQ 2048
#define MTOT (BATCH*SEQ)   // 4096
#define KVBLK 64
#define NT (SEQ/KVBLK)     // 32

typedef __attribute__((ext_vector_type(4))) float f32x4;
typedef __attribute__((ext_vector_type(8))) short bf16x8;

// XOR swizzle: LDS(row, c) holds element (row, c ^ ((row&7)<<4)). Involution,
// used identically on the pre-swizzled global source and the ds_read side (G21).
__device__ __forceinline__ uint32_t swz128(uint32_t row, uint32_t cb) {
  return row * 128u + (cb ^ ((row & 7u) << 4));
}
__device__ __forceinline__ uint32_t swz256(uint32_t row, uint32_t cb) {
  return row * 256u + (cb ^ ((row & 7u) << 4));
}

// async global->LDS, 16B per lane
__device__ __forceinline__ void gload16(void* lds, const void* g) {
  __builtin_amdgcn_global_load_lds(
      reinterpret_cast<const __attribute__((address_space(1))) uint32_t*>(
          reinterpret_cast<uintptr_t>(g)),
      reinterpret_cast<__attribute__((address_space(3))) uint32_t*>(
          (uint32_t)reinterpret_cast<uintptr_t>(lds)),
      16, 0, 0);
}

// ---------------- cast fp32 -> bf16, all three inputs in one launch ----------------
__global__ __launch_bounds__(256) void cast3(const float* __restrict__ q,
                                             const float* __restrict__ k,
                                             const float* __restrict__ v,
                                             __hip_bfloat16* __restrict__ out) {
  const float* src = blockIdx.y == 0 ? q : (blockIdx.y == 1 ? k : v);
  const size_t NE = (size_t)MTOT * D_MODEL;
  size_t i = ((size_t)blockIdx.x * 256 + threadIdx.x) * 8;
  float4 a = *reinterpret_cast<const float4*>(src + i);
  float4 b = *reinterpret_cast<const float4*>(src + i + 4);
  __hip_bfloat16 o[8] = {__float2bfloat16(a.x), __float2bfloat16(a.y),
                         __float2bfloat16(a.z), __float2bfloat16(a.w),
                         __float2bfloat16(b.x), __float2bfloat16(b.y),
                         __float2bfloat16(b.z), __float2bfloat16(b.w)};
  *reinterpret_cast<uint4*>(out + blockIdx.y * NE + i) =
      *reinterpret_cast<const uint4*>(o);
}

// ---------------- transpose+cast all four weights in one launch ----------------
__global__ __launch_bounds__(256)
void transpose4(const float* __restrict__ s0, const float* __restrict__ s1,
                const float* __restrict__ s2, const float* __restrict__ s3,
                __hip_bfloat16* __restrict__ d0, __hip_bfloat16* __restrict__ d1,
                __hip_bfloat16* __restrict__ d2, __hip_bfloat16* __restrict__ d3) {
  const float* W = blockIdx.z == 0 ? s0 : blockIdx.z == 1 ? s1 : blockIdx.z == 2 ? s2 : s3;
  __hip_bfloat16* Wt = blockIdx.z == 0 ? d0 : blockIdx.z == 1 ? d1 : blockIdx.z == 2 ? d2 : d3;
  __shared__ float t[32][33];
  const int x = threadIdx.x, y = threadIdx.y;
  const int n0 = blockIdx.x * 32, k0 = blockIdx.y * 32;
#pragma unroll
  for (int i = 0; i < 4; ++i)
    t[y + i * 8][x] = W[(size_t)(k0 + y + i * 8) * D_MODEL + n0 + x];
  __syncthreads();
#pragma unroll
  for (int i = 0; i < 4; ++i)
    Wt[(size_t)(n0 + y + i * 8) * D_MODEL + k0 + x] = __float2bfloat16(t[x][y + i * 8]);
}

// ---------------- 128x128 bf16 GEMM, global_load_lds staging (m97 structure) ----------------
struct GemmArgs {
  const __hip_bfloat16* A;   // [M][K]
  const __hip_bfloat16* B;   // [N][K]  (W^T)
  const float* bias;         // [N]
  void* out;
  int mode;  // 0: bf16 [bh][s][hd]; 1: bf16 [bh][hd][s]; 2: fp32 [row][col]
};

__global__ __launch_bounds__(256)
void gemm_gl(GemmArgs g0, GemmArgs g1, GemmArgs g2, int K) {
  __shared__ char ldsA[128 * 128];
  __shared__ char ldsB[128 * 128];
  GemmArgs ga = blockIdx.z == 0 ? g0 : (blockIdx.z == 1 ? g1 : g2);

  const int tid = threadIdx.x, lane = tid & 63, wid = tid >> 6;
  const int lrow = lane & 15, lko = (lane >> 4) * 8, rbase = (lane >> 4) * 4;
  const int m0 = blockIdx.x * 128, n0 = blockIdx.y * 128;
  const size_t ldb = (size_t)K * 2;

  const int srow = lane >> 3;                       // row within call
  const int sca = ((lane & 7) * 16) ^ (srow << 4);  // pre-swizzled source col
  const char* Ab = (const char*)ga.A + (size_t)(m0 + wid * 32 + srow) * ldb + sca;
  const char* Bb = (const char*)ga.B + (size_t)(n0 + wid * 32 + srow) * ldb + sca;
  char* lA = ldsA + wid * 32 * 128;
  char* lB = ldsB + wid * 32 * 128;

  f32x4 acc[4][4];
  const f32x4 fz = {0.f, 0.f, 0.f, 0.f};
#pragma unroll
  for (int m = 0; m < 4; ++m)
#pragma unroll
    for (int n = 0; n < 4; ++n) acc[m][n] = fz;

  const int wm = (wid >> 1) * 64, wn = (wid & 1) * 64;

  for (int kt = 0; kt < K; kt += 64) {
    __syncthreads();
#pragma unroll
    for (int i = 0; i < 4; ++i) {
      gload16(lA + i * 8 * 128, Ab + (size_t)i * 8 * ldb + kt * 2);
      gload16(lB + i * 8 * 128, Bb + (size_t)i * 8 * ldb + kt * 2);
    }
    __syncthreads();
#pragma unroll
    for (int kk = 0; kk < 64; kk += 32) {
      bf16x8 af[4], bf[4];
#pragma unroll
      for (int m = 0; m < 4; ++m)
        af[m] = *reinterpret_cast<const bf16x8*>(&ldsA[swz128(wm + m * 16 + lrow, (kk + lko) * 2)]);
#pragma unroll
      for (int n = 0; n < 4; ++n)
        bf[n] = *reinterpret_cast<const bf16x8*>(&ldsB[swz128(wn + n * 16 + lrow, (kk + lko) * 2)]);
#pragma unroll
      for (int m = 0; m < 4; ++m)
#pragma unroll
        for (int n = 0; n < 4; ++n)
          acc[m][n] = __builtin_amdgcn_mfma_f32_16x16x32_bf16(af[m], bf[n], acc[m][n], 0, 0, 0);
    }
  }

  if (ga.mode == 2) {
#pragma unroll
    for (int m = 0; m < 4; ++m)
#pragma unroll
      for (int n = 0; n < 4; ++n) {
        const int col = n0 + wn + n * 16 + lrow;
        const float bv = ga.bias[col];
#pragma unroll
        for (int r = 0; r < 4; ++r) {
          const int row = m0 + wm + m * 16 + rbase + r;
          reinterpret_cast<float*>(ga.out)[(size_t)row * D_MODEL + col] = acc[m][n][r] + bv;
        }
      }
  } else if (ga.mode == 0) {
#pragma unroll
    for (int m = 0; m < 4; ++m)
#pragma unroll
      for (int n = 0; n < 4; ++n) {
        const int col = n0 + wn + n * 16 + lrow;
        const float bv = ga.bias[col];
        const int h = col >> 7, hd = col & 127;
#pragma unroll
        for (int r = 0; r < 4; ++r) {
          const int row = m0 + wm + m * 16 + rbase + r;
          const int b = row >> 11, s = row & 2047;
          reinterpret_cast<__hip_bfloat16*>(ga.out)[((size_t)(b * NHEAD + h) * SEQ + s) * HDIM + hd] =
              __float2bfloat16(acc[m][n][r] + bv);
        }
      }
  } else {
#pragma unroll
    for (int m = 0; m < 4; ++m)
#pragma unroll
      for (int n = 0; n < 4; ++n) {
        const int col = n0 + wn + n * 16 + lrow;
        const float bv = ga.bias[col];
        const int h = col >> 7, hd = col & 127;
#pragma unroll
        for (int r = 0; r < 4; ++r) {
          const int row = m0 + wm + m * 16 + rbase + r;
          const int b = row >> 11, s = row & 2047;
          reinterpret_cast<__hip_bfloat16*>(ga.out)[((size_t)(b * NHEAD + h) * HDIM + hd) * SEQ + s] =
              __float2bfloat16(acc[m][n][r] + bv);
        }
      }
  }
}

// ---------------- fused ReLU attention v4: 2-way split-KV ----------------
// QBLK=128, 8 waves, grid 512 = 2 blocks/CU (64KB LDS). Each block does half
// the KV range; attn-weight cols disjoint; ctx partials fp32 -> ws, combined
// by a separate kernel. Block B's compute hides block A's store drain.
__global__ __launch_bounds__(512, 4)
void attn_v4(const __hip_bfloat16* __restrict__ Qh,   // [bh][s][hd]
             const __hip_bfloat16* __restrict__ Kh,   // [bh][s][hd]
             const __hip_bfloat16* __restrict__ Vt,   // [bh][hd][s]
             float* __restrict__ attn,                // [bh][q][k]
             float* __restrict__ ctxp) {              // [2][b][s][h*128+hd] fp32
  __shared__ char ldsK[2][KVBLK * 256];   // 32KB, rows=key, 256B (128 hd)
  __shared__ char ldsV[HDIM * 128];       // 16KB, rows=hd, 128B (64 key)
  __shared__ char ldsP[128 * 128];        // 16KB, rows=q, 128B (64 key)

  const int tid = threadIdx.x, lane = tid & 63, wid = tid >> 6;
  const int lrow = lane & 15, lko = (lane >> 4) * 8, rbase = (lane >> 4) * 4;
  const int wqq = (wid >> 1) * 32;   // q offset (4 groups)
  const int wqk = (wid & 1) * 32;    // key offset in QK (2 groups)
  const int whd = (wid & 1) * 64;    // hd offset in PV (2 groups)

  // XCD-aware decode: XCD x gets bh {2x, 2x+1}; per bh: 2 parts x 16 q-tiles
  const int raw = blockIdx.x;
  const int xcd = raw & 7, slot = raw >> 3;      // slot 0..63
  const int bh = xcd * 2 + (slot >> 5);
  const int rem = slot & 31;
  const int part = rem >> 4;                     // KV half
  const int q0 = (rem & 15) * 128;
  const int t0 = part * (NT / 2), t1 = t0 + (NT / 2);

  const char* Kg = (const char*)Kh + (size_t)bh * SEQ * HDIM * 2;
  const char* Vg = (const char*)Vt + (size_t)bh * HDIM * SEQ * 2;
  const __hip_bfloat16* Qg = Qh + ((size_t)bh * SEQ + q0) * HDIM;
  float* attnb = attn + ((size_t)bh * SEQ + q0) * SEQ;
  float* ctxb = ctxp + (size_t)part * MTOT * D_MODEL;

  const int krl = lane >> 4;                        // K-stage: row in 4-row call
  const int kcb = (lane & 15) * 16;
  const int vrl = lane >> 3;                        // V-stage: row in 8-row call
  const int vsc = ((lane & 7) * 16) ^ (vrl << 4);   // pre-swizzled V source col

  // stage K tile t0 (t0 is even -> buffer 0)
#pragma unroll
  for (int j = 0; j < 2; ++j) {
    const int rr = wid * 8 + j * 4 + krl;
    gload16((char*)ldsK[0] + (wid * 8 + j * 4) * 256,
            Kg + (size_t)(t0 * KVBLK + rr) * 256 + (kcb ^ ((rr & 7) << 4)));
  }

  // Q -> registers (reused all 16 tiles)
  bf16x8 qf[2][4];
#pragma unroll
  for (int m = 0; m < 2; ++m)
#pragma unroll
    for (int kk = 0; kk < 4; ++kk)
      qf[m][kk] = *reinterpret_cast<const bf16x8*>(
          Qg + (size_t)(wqq + m * 16 + lrow) * HDIM + kk * 32 + lko);

  f32x4 cacc[2][4];
  const f32x4 fz = {0.f, 0.f, 0.f, 0.f};
#pragma unroll
  for (int m = 0; m < 2; ++m)
#pragma unroll
    for (int n = 0; n < 4; ++n) cacc[m][n] = fz;

  const float scale = 0.08838834764831845f;  // 1/sqrt(128)
  __syncthreads();

  for (int t = t0; t < t1; ++t) {
    const int b = t & 1;
    // stage V_t (single buffer; prev PV done at loop-end barrier)
#pragma unroll
    for (int j = 0; j < 2; ++j) {
      const int rv = wid * 16 + j * 8 + vrl;
      gload16((char*)ldsV + (wid * 16 + j * 8) * 128,
              Vg + (size_t)rv * (SEQ * 2) + t * 128 + vsc);
    }
    if (t + 1 < t1) {  // prefetch next K tile into other buffer
#pragma unroll
      for (int j = 0; j < 2; ++j) {
        const int rr = wid * 8 + j * 4 + krl;
        gload16((char*)ldsK[b ^ 1] + (wid * 8 + j * 4) * 256,
                Kg + (size_t)((t + 1) * KVBLK + rr) * 256 + (kcb ^ ((rr & 7) << 4)));
      }
    }

    // QK^T : S[128q x 64k], wave = 32q x 32k (reads ldsK[b], ready last iter)
    f32x4 sacc[2][2];
#pragma unroll
    for (int m = 0; m < 2; ++m)
#pragma unroll
      for (int n = 0; n < 2; ++n) sacc[m][n] = fz;
    __builtin_amdgcn_s_setprio(1);
#pragma unroll
    for (int kk = 0; kk < 4; ++kk) {
      bf16x8 kf[2];
#pragma unroll
      for (int n = 0; n < 2; ++n)
        kf[n] = *reinterpret_cast<const bf16x8*>(
            &ldsK[b][swz256(wqk + n * 16 + lrow, (kk * 32 + lko) * 2)]);
#pragma unroll
      for (int m = 0; m < 2; ++m)
#pragma unroll
        for (int n = 0; n < 2; ++n)
          sacc[m][n] = __builtin_amdgcn_mfma_f32_16x16x32_bf16(qf[m][kk], kf[n], sacc[m][n], 0, 0, 0);
    }
    __builtin_amdgcn_s_setprio(0);

    // scale + relu -> global fp32 attn + bf16 P to LDS
#pragma unroll
    for (int m = 0; m < 2; ++m)
#pragma unroll
      for (int n = 0; n < 2; ++n)
#pragma unroll
        for (int r = 0; r < 4; ++r) {
          const int ql = wqq + m * 16 + rbase + r;
          const int kl = wqk + n * 16 + lrow;
          const float s = fmaxf(sacc[m][n][r] * scale, 0.f);
          attnb[(size_t)ql * SEQ + t * KVBLK + kl] = s;
          *reinterpret_cast<__hip_bfloat16*>(&ldsP[swz128(ql, kl * 2)]) = __float2bfloat16(s);
        }
    __syncthreads();  // P + V_t + K_{t+1} ready

    // PV : ctx += P[128q x 64k] * V[64k x 128hd], wave = 32q x 64hd
    __builtin_amdgcn_s_setprio(1);
#pragma unroll
    for (int kk = 0; kk < 2; ++kk) {
      bf16x8 pf[2], vf[4];
#pragma unroll
      for (int m = 0; m < 2; ++m)
        pf[m] = *reinterpret_cast<const bf16x8*>(
            &ldsP[swz128(wqq + m * 16 + lrow, (kk * 32 + lko) * 2)]);
#pragma unroll
      for (int n = 0; n < 4; ++n)
        vf[n] = *reinterpret_cast<const bf16x8*>(
            &ldsV[swz128(whd + n * 16 + lrow, (kk * 32 + lko) * 2)]);
#pragma unroll
      for (int m = 0; m < 2; ++m)
#pragma unroll
        for (int n = 0; n < 4; ++n)
          cacc[m][n] = __builtin_amdgcn_mfma_f32_16x16x32_bf16(pf[m], vf[n], cacc[m][n], 0, 0, 0);
    }
    __builtin_amdgcn_s_setprio(0);
    __syncthreads();  // PV reads of P/V done before next overwrite
  }

  // ctx partial fp32 [part][b][s][h*128+hd]
  const int bb = bh >> 3, h = bh & 7;
#pragma unroll
  for (int m = 0; m < 2; ++m)
#pragma unroll
    for (int n = 0; n < 4; ++n)
#pragma unroll
      for (int r = 0; r < 4; ++r) {
        const int srow = q0 + wqq + m * 16 + rbase + r;
        const int hd = whd + n * 16 + lrow;
        ctxb[((size_t)(bb * SEQ + srow)) * D_MODEL + h * HDIM + hd] = cacc[m][n][r];
      }
}

// ---------------- combine: ctx = bf16(ctxp[0] + ctxp[1]) ----------------
__global__ __launch_bounds__(256)
void combine2(const float* __restrict__ p, __hip_bfloat16* __restrict__ ctx) {
  const size_t NE = (size_t)MTOT * D_MODEL;
  size_t i = ((size_t)blockIdx.x * 256 + threadIdx.x) * 8;
  f32x4 a0 = *reinterpret_cast<const f32x4*>(p + i);
  f32x4 a1 = *reinterpret_cast<const f32x4*>(p + i + 4);
  f32x4 b0 = *reinterpret_cast<const f32x4*>(p + NE + i);
  f32x4 b1 = *reinterpret_cast<const f32x4*>(p + NE + i + 4);
  f32x4 s0 = a0 + b0, s1 = a1 + b1;
  __hip_bfloat16 o[8] = {__float2bfloat16(s0[0]), __float2bfloat16(s0[1]),
                         __float2bfloat16(s0[2]), __float2bfloat16(s0[3]),
                         __float2bfloat16(s1[0]), __float2bfloat16(s1[1]),
                         __float2bfloat16(s1[2]), __float2bfloat16(s1[3])};
  *reinterpret_cast<uint4*>(ctx + i) = *reinterpret_cast<const uint4*>(o);
}

extern "C" void kernel_launch(void* const* d_in, const int* in_sizes, int n_in,
                              void* d_out, int out_size, void* d_ws, size_t ws_size,
                              hipStream_t stream) {
  const float* q  = (const float*)d_in[0];
  const float* k  = (const float*)d_in[1];
  const float* v  = (const float*)d_in[2];
  const float* Wq = (const float*)d_in[3];
  const float* bq = (const float*)d_in[4];
  const float* Wk = (const float*)d_in[5];
  const float* bk = (const float*)d_in[6];
  const float* Wv = (const float*)d_in[7];
  const float* bv = (const float*)d_in[8];
  const float* Wo = (const float*)d_in[9];
  const float* bo = (const float*)d_in[10];

  char* ws = (char*)d_ws;
  const size_t NE = (size_t)MTOT * D_MODEL;     // 4194304
  const size_t WE = (size_t)D_MODEL * D_MODEL;  // 1048576
  __hip_bfloat16* qb  = (__hip_bfloat16*)ws;
  __hip_bfloat16* kb  = qb + NE;
  __hip_bfloat16* vb  = kb + NE;
  __hip_bfloat16* Wqt = vb + NE;
  __hip_bfloat16* Wkt = Wqt + WE;
  __hip_bfloat16* Wvt = Wkt + WE;
  __hip_bfloat16* Wot = Wvt + WE;
  __hip_bfloat16* Qh  = Wot + WE;
  __hip_bfloat16* Kh  = Qh + NE;
  __hip_bfloat16* Vt  = Kh + NE;
  __hip_bfloat16* ctx = Vt + NE;
  float* ctxp = (float*)(ctx + NE);             // 2 x NE fp32 partials

  cast3<<<dim3((unsigned)(NE / 8 / 256), 3), 256, 0, stream>>>(q, k, v, qb);
  transpose4<<<dim3(32, 32, 4), dim3(32, 8), 0, stream>>>(Wq, Wk, Wv, Wo, Wqt, Wkt, Wvt, Wot);

  GemmArgs gq{qb, Wqt, bq, Qh, 0};
  GemmArgs gk{kb, Wkt, bk, Kh, 0};
  GemmArgs gv{vb, Wvt, bv, Vt, 1};
  gemm_gl<<<dim3(32, 8, 3), 256, 0, stream>>>(gq, gk, gv, D_MODEL);

  float* outp  = (float*)d_out;
  float* attnp = outp + NE;
  attn_v4<<<512, 512, 0, stream>>>(Qh, Kh, Vt, attnp, ctxp);
  combine2<<<(unsigned)(NE / 8 / 256), 256, 0, stream>>>(ctxp, ctx);

  GemmArgs go{ctx, Wot, bo, d_out, 2};
  gemm_gl<<<dim3(32, 8, 1), 256, 0, stream>>>(go, go, go, D_MODEL);
}

// Round 6
// 151.944 us; speedup vs baseline: 2.0215x; 2.0215x over previous
//
#include <hip/hip_runtime.h>
#include <hip/hip_bf16.h>
#include <stdint.h>

#define D_MODEL 1024
#define NHEAD 8
#define HDIM 128
#define BATCH 2
#define SEQ 2048
#define MTOT (BATCH*SEQ)   // 4096
#define KVBLK 64
#define NT (SEQ/KVBLK)     // 32

typedef __attribute__((ext_vector_type(4))) float f32x4;
typedef __attribute__((ext_vector_type(8))) short bf16x8;

// XOR swizzle: LDS(row, c) holds element (row, c ^ ((row&7)<<4)). Involution,
// used identically on the pre-swizzled global source and the ds_read side (G21).
__device__ __forceinline__ uint32_t swz128(uint32_t row, uint32_t cb) {
  return row * 128u + (cb ^ ((row & 7u) << 4));
}
__device__ __forceinline__ uint32_t swz256(uint32_t row, uint32_t cb) {
  return row * 256u + (cb ^ ((row & 7u) << 4));
}

// async global->LDS, 16B per lane
__device__ __forceinline__ void gload16(void* lds, const void* g) {
  __builtin_amdgcn_global_load_lds(
      reinterpret_cast<const __attribute__((address_space(1))) uint32_t*>(
          reinterpret_cast<uintptr_t>(g)),
      reinterpret_cast<__attribute__((address_space(3))) uint32_t*>(
          (uint32_t)reinterpret_cast<uintptr_t>(lds)),
      16, 0, 0);
}

// Counted barriers (T4): keep attn stores in flight across the barrier.
// mid: only LDS ops must be visible (P writes); prefetch correctness is
// guaranteed by the PREVIOUS end barrier's vmcnt(16).
__device__ __forceinline__ void barrier_lgkm() {
  asm volatile("s_waitcnt lgkmcnt(0)\n\ts_barrier" ::: "memory");
}
// end: retire the 4 oldest vmem ops (this iter's K/V gloads) + all DS;
// <=16 attn stores may stay in flight.
__device__ __forceinline__ void barrier_vm16() {
  asm volatile("s_waitcnt vmcnt(16) lgkmcnt(0)\n\ts_barrier" ::: "memory");
}

// ---------------- cast fp32 -> bf16, all three inputs in one launch ----------------
__global__ __launch_bounds__(256) void cast3(const float* __restrict__ q,
                                             const float* __restrict__ k,
                                             const float* __restrict__ v,
                                             __hip_bfloat16* __restrict__ out) {
  const float* src = blockIdx.y == 0 ? q : (blockIdx.y == 1 ? k : v);
  const size_t NE = (size_t)MTOT * D_MODEL;
  size_t i = ((size_t)blockIdx.x * 256 + threadIdx.x) * 8;
  float4 a = *reinterpret_cast<const float4*>(src + i);
  float4 b = *reinterpret_cast<const float4*>(src + i + 4);
  __hip_bfloat16 o[8] = {__float2bfloat16(a.x), __float2bfloat16(a.y),
                         __float2bfloat16(a.z), __float2bfloat16(a.w),
                         __float2bfloat16(b.x), __float2bfloat16(b.y),
                         __float2bfloat16(b.z), __float2bfloat16(b.w)};
  *reinterpret_cast<uint4*>(out + blockIdx.y * NE + i) =
      *reinterpret_cast<const uint4*>(o);
}

// ---------------- transpose+cast all four weights in one launch ----------------
__global__ __launch_bounds__(256)
void transpose4(const float* __restrict__ s0, const float* __restrict__ s1,
                const float* __restrict__ s2, const float* __restrict__ s3,
                __hip_bfloat16* __restrict__ d0, __hip_bfloat16* __restrict__ d1,
                __hip_bfloat16* __restrict__ d2, __hip_bfloat16* __restrict__ d3) {
  const float* W = blockIdx.z == 0 ? s0 : blockIdx.z == 1 ? s1 : blockIdx.z == 2 ? s2 : s3;
  __hip_bfloat16* Wt = blockIdx.z == 0 ? d0 : blockIdx.z == 1 ? d1 : blockIdx.z == 2 ? d2 : d3;
  __shared__ float t[32][33];
  const int x = threadIdx.x, y = threadIdx.y;
  const int n0 = blockIdx.x * 32, k0 = blockIdx.y * 32;
#pragma unroll
  for (int i = 0; i < 4; ++i)
    t[y + i * 8][x] = W[(size_t)(k0 + y + i * 8) * D_MODEL + n0 + x];
  __syncthreads();
#pragma unroll
  for (int i = 0; i < 4; ++i)
    Wt[(size_t)(n0 + y + i * 8) * D_MODEL + k0 + x] = __float2bfloat16(t[x][y + i * 8]);
}

// ---------------- 128x128 bf16 GEMM, global_load_lds staging (m97 structure) ----------------
struct GemmArgs {
  const __hip_bfloat16* A;   // [M][K]
  const __hip_bfloat16* B;   // [N][K]  (W^T)
  const float* bias;         // [N]
  void* out;
  int mode;  // 0: bf16 [bh][s][hd]; 1: bf16 [bh][hd][s]; 2: fp32 [row][col]
};

__global__ __launch_bounds__(256)
void gemm_gl(GemmArgs g0, GemmArgs g1, GemmArgs g2, int K) {
  __shared__ char ldsA[128 * 128];
  __shared__ char ldsB[128 * 128];
  GemmArgs ga = blockIdx.z == 0 ? g0 : (blockIdx.z == 1 ? g1 : g2);

  const int tid = threadIdx.x, lane = tid & 63, wid = tid >> 6;
  const int lrow = lane & 15, lko = (lane >> 4) * 8, rbase = (lane >> 4) * 4;
  const int m0 = blockIdx.x * 128, n0 = blockIdx.y * 128;
  const size_t ldb = (size_t)K * 2;

  const int srow = lane >> 3;                       // row within call
  const int sca = ((lane & 7) * 16) ^ (srow << 4);  // pre-swizzled source col
  const char* Ab = (const char*)ga.A + (size_t)(m0 + wid * 32 + srow) * ldb + sca;
  const char* Bb = (const char*)ga.B + (size_t)(n0 + wid * 32 + srow) * ldb + sca;
  char* lA = ldsA + wid * 32 * 128;
  char* lB = ldsB + wid * 32 * 128;

  f32x4 acc[4][4];
  const f32x4 fz = {0.f, 0.f, 0.f, 0.f};
#pragma unroll
  for (int m = 0; m < 4; ++m)
#pragma unroll
    for (int n = 0; n < 4; ++n) acc[m][n] = fz;

  const int wm = (wid >> 1) * 64, wn = (wid & 1) * 64;

  for (int kt = 0; kt < K; kt += 64) {
    __syncthreads();
#pragma unroll
    for (int i = 0; i < 4; ++i) {
      gload16(lA + i * 8 * 128, Ab + (size_t)i * 8 * ldb + kt * 2);
      gload16(lB + i * 8 * 128, Bb + (size_t)i * 8 * ldb + kt * 2);
    }
    __syncthreads();
#pragma unroll
    for (int kk = 0; kk < 64; kk += 32) {
      bf16x8 af[4], bf[4];
#pragma unroll
      for (int m = 0; m < 4; ++m)
        af[m] = *reinterpret_cast<const bf16x8*>(&ldsA[swz128(wm + m * 16 + lrow, (kk + lko) * 2)]);
#pragma unroll
      for (int n = 0; n < 4; ++n)
        bf[n] = *reinterpret_cast<const bf16x8*>(&ldsB[swz128(wn + n * 16 + lrow, (kk + lko) * 2)]);
#pragma unroll
      for (int m = 0; m < 4; ++m)
#pragma unroll
        for (int n = 0; n < 4; ++n)
          acc[m][n] = __builtin_amdgcn_mfma_f32_16x16x32_bf16(af[m], bf[n], acc[m][n], 0, 0, 0);
    }
  }

  if (ga.mode == 2) {
#pragma unroll
    for (int m = 0; m < 4; ++m)
#pragma unroll
      for (int n = 0; n < 4; ++n) {
        const int col = n0 + wn + n * 16 + lrow;
        const float bv = ga.bias[col];
#pragma unroll
        for (int r = 0; r < 4; ++r) {
          const int row = m0 + wm + m * 16 + rbase + r;
          reinterpret_cast<float*>(ga.out)[(size_t)row * D_MODEL + col] = acc[m][n][r] + bv;
        }
      }
  } else if (ga.mode == 0) {
#pragma unroll
    for (int m = 0; m < 4; ++m)
#pragma unroll
      for (int n = 0; n < 4; ++n) {
        const int col = n0 + wn + n * 16 + lrow;
        const float bv = ga.bias[col];
        const int h = col >> 7, hd = col & 127;
#pragma unroll
        for (int r = 0; r < 4; ++r) {
          const int row = m0 + wm + m * 16 + rbase + r;
          const int b = row >> 11, s = row & 2047;
          reinterpret_cast<__hip_bfloat16*>(ga.out)[((size_t)(b * NHEAD + h) * SEQ + s) * HDIM + hd] =
              __float2bfloat16(acc[m][n][r] + bv);
        }
      }
  } else {
#pragma unroll
    for (int m = 0; m < 4; ++m)
#pragma unroll
      for (int n = 0; n < 4; ++n) {
        const int col = n0 + wn + n * 16 + lrow;
        const float bv = ga.bias[col];
        const int h = col >> 7, hd = col & 127;
#pragma unroll
        for (int r = 0; r < 4; ++r) {
          const int row = m0 + wm + m * 16 + rbase + r;
          const int b = row >> 11, s = row & 2047;
          reinterpret_cast<__hip_bfloat16*>(ga.out)[((size_t)(b * NHEAD + h) * HDIM + hd) * SEQ + s] =
              __float2bfloat16(acc[m][n][r] + bv);
        }
      }
  }
}

// ---------------- fused ReLU attention v2 (r2-proven) + counted-vmcnt barriers ----------------
// 512 threads (8 waves), QBLK=128, K/V double-buffered gload_lds prefetch, 80KB LDS.
// XCD swizzle: 2 bh per XCD (K+V 2MB < 4MB L2). Per wave per iter: 4 gloads then
// 16 attn stores; end barrier vmcnt(16) retires only the gloads.
__global__ __launch_bounds__(512)
void attn_v2(const __hip_bfloat16* __restrict__ Qh,   // [bh][s][hd]
             const __hip_bfloat16* __restrict__ Kh,   // [bh][s][hd]
             const __hip_bfloat16* __restrict__ Vt,   // [bh][hd][s]
             float* __restrict__ attn,                // [bh][q][k]
             __hip_bfloat16* __restrict__ ctx) {      // [b][s][h*128+hd]
  __shared__ char ldsK[2][KVBLK * 256];   // 2 x 16KB, rows=key, 256B (128 hd)
  __shared__ char ldsV[2][HDIM * 128];    // 2 x 16KB, rows=hd, 128B (64 key)
  __shared__ char ldsP[128 * 128];        // 16KB, rows=q, 128B (64 key)

  const int tid = threadIdx.x, lane = tid & 63, wid = tid >> 6;
  const int lrow = lane & 15, lko = (lane >> 4) * 8, rbase = (lane >> 4) * 4;
  const int wqq = (wid >> 1) * 32;   // q offset (4 groups)
  const int wqk = (wid & 1) * 32;    // key offset in QK (2 groups)
  const int whd = (wid & 1) * 64;    // hd offset in PV (2 groups)

  // XCD-aware decode: XCD x gets bh {2x, 2x+1}, 16 q-tiles each
  const int raw = blockIdx.x;
  const int xcd = raw & 7, slot = raw >> 3;
  const int bh = xcd * 2 + (slot >> 4);
  const int q0 = (slot & 15) * 128;

  const char* Kg = (const char*)Kh + (size_t)bh * SEQ * HDIM * 2;
  const char* Vg = (const char*)Vt + (size_t)bh * HDIM * SEQ * 2;
  const __hip_bfloat16* Qg = Qh + ((size_t)bh * SEQ + q0) * HDIM;
  float* attnb = attn + ((size_t)bh * SEQ + q0) * SEQ;

  const int krl = lane >> 4;                        // K-stage: row in 4-row call
  const int kcb = (lane & 15) * 16;
  const int vrl = lane >> 3;                        // V-stage: row in 8-row call
  const int vsc = ((lane & 7) * 16) ^ (vrl << 4);   // pre-swizzled V source col

  // stage tile 0
#pragma unroll
  for (int j = 0; j < 2; ++j) {
    const int rr = wid * 8 + j * 4 + krl;
    gload16((char*)ldsK[0] + (wid * 8 + j * 4) * 256,
            Kg + (size_t)rr * 256 + (kcb ^ ((rr & 7) << 4)));
    const int rv = wid * 16 + j * 8 + vrl;
    gload16((char*)ldsV[0] + (wid * 16 + j * 8) * 128,
            Vg + (size_t)rv * (SEQ * 2) + vsc);
  }

  // Q -> registers (reused all 32 tiles)
  bf16x8 qf[2][4];
#pragma unroll
  for (int m = 0; m < 2; ++m)
#pragma unroll
    for (int kk = 0; kk < 4; ++kk)
      qf[m][kk] = *reinterpret_cast<const bf16x8*>(
          Qg + (size_t)(wqq + m * 16 + lrow) * HDIM + kk * 32 + lko);

  f32x4 cacc[2][4];
  const f32x4 fz = {0.f, 0.f, 0.f, 0.f};
#pragma unroll
  for (int m = 0; m < 2; ++m)
#pragma unroll
    for (int n = 0; n < 4; ++n) cacc[m][n] = fz;

  const float scale = 0.08838834764831845f;  // 1/sqrt(128)
  __syncthreads();   // full drain: tile 0 + Q regs ready

  for (int t = 0; t < NT; ++t) {
    const int b = t & 1;
    if (t + 1 < NT) {  // prefetch next K/V tile into other buffer (4 gloads/wave)
#pragma unroll
      for (int j = 0; j < 2; ++j) {
        const int rr = wid * 8 + j * 4 + krl;
        gload16((char*)ldsK[b ^ 1] + (wid * 8 + j * 4) * 256,
                Kg + (size_t)((t + 1) * KVBLK + rr) * 256 + (kcb ^ ((rr & 7) << 4)));
        const int rv = wid * 16 + j * 8 + vrl;
        gload16((char*)ldsV[b ^ 1] + (wid * 16 + j * 8) * 128,
                Vg + (size_t)rv * (SEQ * 2) + (t + 1) * 128 + vsc);
      }
    }

    // QK^T : S[128q x 64k], wave = 32q x 32k (ldsK[b] complete per prev end-barrier)
    f32x4 sacc[2][2];
#pragma unroll
    for (int m = 0; m < 2; ++m)
#pragma unroll
      for (int n = 0; n < 2; ++n) sacc[m][n] = fz;
    __builtin_amdgcn_s_setprio(1);
#pragma unroll
    for (int kk = 0; kk < 4; ++kk) {
      bf16x8 kf[2];
#pragma unroll
      for (int n = 0; n < 2; ++n)
        kf[n] = *reinterpret_cast<const bf16x8*>(
            &ldsK[b][swz256(wqk + n * 16 + lrow, (kk * 32 + lko) * 2)]);
#pragma unroll
      for (int m = 0; m < 2; ++m)
#pragma unroll
        for (int n = 0; n < 2; ++n)
          sacc[m][n] = __builtin_amdgcn_mfma_f32_16x16x32_bf16(qf[m][kk], kf[n], sacc[m][n], 0, 0, 0);
    }
    __builtin_amdgcn_s_setprio(0);

    // scale + relu -> global fp32 attn (16 stores/wave, left in flight) + bf16 P to LDS
#pragma unroll
    for (int m = 0; m < 2; ++m)
#pragma unroll
      for (int n = 0; n < 2; ++n)
#pragma unroll
        for (int r = 0; r < 4; ++r) {
          const int ql = wqq + m * 16 + rbase + r;
          const int kl = wqk + n * 16 + lrow;
          const float s = fmaxf(sacc[m][n][r] * scale, 0.f);
          attnb[(size_t)ql * SEQ + t * KVBLK + kl] = s;
          *reinterpret_cast<__hip_bfloat16*>(&ldsP[swz128(ql, kl * 2)]) = __float2bfloat16(s);
        }
    barrier_lgkm();  // P visible; V for this iter proven complete last end-barrier

    // PV : ctx += P[128q x 64k] * V[64k x 128hd], wave = 32q x 64hd
    __builtin_amdgcn_s_setprio(1);
#pragma unroll
    for (int kk = 0; kk < 2; ++kk) {
      bf16x8 pf[2], vf[4];
#pragma unroll
      for (int m = 0; m < 2; ++m)
        pf[m] = *reinterpret_cast<const bf16x8*>(
            &ldsP[swz128(wqq + m * 16 + lrow, (kk * 32 + lko) * 2)]);
#pragma unroll
      for (int n = 0; n < 4; ++n)
        vf[n] = *reinterpret_cast<const bf16x8*>(
            &ldsV[b][swz128(whd + n * 16 + lrow, (kk * 32 + lko) * 2)]);
#pragma unroll
      for (int m = 0; m < 2; ++m)
#pragma unroll
        for (int n = 0; n < 4; ++n)
          cacc[m][n] = __builtin_amdgcn_mfma_f32_16x16x32_bf16(pf[m], vf[n], cacc[m][n], 0, 0, 0);
    }
    __builtin_amdgcn_s_setprio(0);
    barrier_vm16();  // retire this iter's 4 gloads (next tile ready); stores stay in flight
  }

  // ctx bf16 [b][s][h*128+hd]
  const int bb = bh >> 3, h = bh & 7;
#pragma unroll
  for (int m = 0; m < 2; ++m)
#pragma unroll
    for (int n = 0; n < 4; ++n)
#pragma unroll
      for (int r = 0; r < 4; ++r) {
        const int srow = q0 + wqq + m * 16 + rbase + r;
        const int hd = whd + n * 16 + lrow;
        ctx[((size_t)(bb * SEQ + srow)) * D_MODEL + h * HDIM + hd] =
            __float2bfloat16(cacc[m][n][r]);
      }
}

extern "C" void kernel_launch(void* const* d_in, const int* in_sizes, int n_in,
                              void* d_out, int out_size, void* d_ws, size_t ws_size,
                              hipStream_t stream) {
  const float* q  = (const float*)d_in[0];
  const float* k  = (const float*)d_in[1];
  const float* v  = (const float*)d_in[2];
  const float* Wq = (const float*)d_in[3];
  const float* bq = (const float*)d_in[4];
  const float* Wk = (const float*)d_in[5];
  const float* bk = (const float*)d_in[6];
  const float* Wv = (const float*)d_in[7];
  const float* bv = (const float*)d_in[8];
  const float* Wo = (const float*)d_in[9];
  const float* bo = (const float*)d_in[10];

  char* ws = (char*)d_ws;
  const size_t NE = (size_t)MTOT * D_MODEL;     // 4194304
  const size_t WE = (size_t)D_MODEL * D_MODEL;  // 1048576
  __hip_bfloat16* qb  = (__hip_bfloat16*)ws;
  __hip_bfloat16* kb  = qb + NE;
  __hip_bfloat16* vb  = kb + NE;
  __hip_bfloat16* Wqt = vb + NE;
  __hip_bfloat16* Wkt = Wqt + WE;
  __hip_bfloat16* Wvt = Wkt + WE;
  __hip_bfloat16* Wot = Wvt + WE;
  __hip_bfloat16* Qh  = Wot + WE;
  __hip_bfloat16* Kh  = Qh + NE;
  __hip_bfloat16* Vt  = Kh + NE;
  __hip_bfloat16* ctx = Vt + NE;

  cast3<<<dim3((unsigned)(NE / 8 / 256), 3), 256, 0, stream>>>(q, k, v, qb);
  transpose4<<<dim3(32, 32, 4), dim3(32, 8), 0, stream>>>(Wq, Wk, Wv, Wo, Wqt, Wkt, Wvt, Wot);

  GemmArgs gq{qb, Wqt, bq, Qh, 0};
  GemmArgs gk{kb, Wkt, bk, Kh, 0};
  GemmArgs gv{vb, Wvt, bv, Vt, 1};
  gemm_gl<<<dim3(32, 8, 3), 256, 0, stream>>>(gq, gk, gv, D_MODEL);

  float* outp  = (float*)d_out;
  float* attnp = outp + NE;
  attn_v2<<<256, 512, 0, stream>>>(Qh, Kh, Vt, attnp, ctx);

  GemmArgs go{ctx, Wot, bo, d_out, 2};
  gemm_gl<<<dim3(32, 8, 1), 256, 0, stream>>>(go, go, go, D_MODEL);
}